// Round 2
// baseline (211.248 us; speedup 1.0000x reference)
//
#include <hip/hip_runtime.h>
#include <hip/hip_bf16.h>

typedef __attribute__((ext_vector_type(8))) short bf16x8;
typedef __attribute__((ext_vector_type(4))) float f32x4;
typedef unsigned short u16;
typedef unsigned int u32;

__device__ __forceinline__ u16 f2bf(float f) {
    u32 u = __float_as_uint(f);
    u = (u + 0x7FFFu + ((u >> 16) & 1u)) >> 16;
    return (u16)u;
}

// ---------- centers: cn2 = c/||c||, bf16, tiled [b][dblk=24][k=256][dd=32] ----------
__global__ __launch_bounds__(256) void k_centers(const float* __restrict__ c, u16* __restrict__ cn) {
    int row = (blockIdx.x << 2) + (threadIdx.x >> 6);   // 0..2047 = b*256+k
    int lane = threadIdx.x & 63;
    int b = row >> 8, k = row & 255;
    const float* src = c + (size_t)row * 768;
    float v[12]; float ss = 0.f;
#pragma unroll
    for (int j = 0; j < 12; ++j) { v[j] = src[lane + (j << 6)]; ss += v[j] * v[j]; }
#pragma unroll
    for (int m = 1; m < 64; m <<= 1) ss += __shfl_xor(ss, m, 64);
    float inv = 1.0f / sqrtf(ss);
#pragma unroll
    for (int j = 0; j < 12; ++j) {
        int d = lane + (j << 6);
        cn[((size_t)((b * 24 + (d >> 5)) * 256 + k) << 5) + (d & 31)] = f2bf(v[j] * inv);
    }
}

// ---------- GEMM1 fused: cos = (x·cn2T)/||x||, softmax over K, write probT[b][k][n], den ----------
__global__ __launch_bounds__(256) void k_gemm1(const float* __restrict__ x, const u16* __restrict__ cn,
                                               u16* __restrict__ probT, float* __restrict__ den) {
    const int b = blockIdx.y;
    const int n0 = blockIdx.x << 6;        // 64-token tile
    const int t = threadIdx.x;
    const int wave = t >> 6, lane = t & 63;
    const int lg = lane >> 4, lr = lane & 15;

    __shared__ union {
        struct { u16 A[64][40]; u16 B[256][40]; } s;   // 5120 + 20480 B
        u16 T[256][72];                                 // 36864 B (stride 144B, 16B-aligned rows)
    } u;
    __shared__ float inv_s[64];
    __shared__ float denp[256];

    denp[t] = 0.f;

    f32x4 acc[16];
#pragma unroll
    for (int f = 0; f < 16; ++f) acc[f] = (f32x4){0.f, 0.f, 0.f, 0.f};

    float sq0 = 0.f, sq1 = 0.f;
    const float* xb = x + ((size_t)b * 8192 + n0) * 768;
    const u16* cnb = cn + (size_t)b * 24 * 256 * 32;

    for (int kb = 0; kb < 24; ++kb) {
        __syncthreads();                      // prev-iter LDS reads done before overwrite
        // stage A: 64 tokens x 32 d, fp32 -> bf16, plus inline sum of squares
#pragma unroll
        for (int p = 0; p < 2; ++p) {
            int idx = (p << 8) + t;
            int r = idx >> 3, c4 = idx & 7;
            float4 vv = *reinterpret_cast<const float4*>(xb + (size_t)r * 768 + (kb << 5) + (c4 << 2));
            float s2 = vv.x * vv.x + vv.y * vv.y + vv.z * vv.z + vv.w * vv.w;
            if (p == 0) sq0 += s2; else sq1 += s2;
            ushort4 w4 = make_ushort4(f2bf(vv.x), f2bf(vv.y), f2bf(vv.z), f2bf(vv.w));
            *reinterpret_cast<ushort4*>(&u.s.A[r][c4 << 2]) = w4;
        }
        // stage B: 256 centers x 32 d bf16 straight copy (contiguous in tiled cn layout)
        const u16* src = cnb + (size_t)kb * 256 * 32;
#pragma unroll
        for (int p = 0; p < 4; ++p) {
            int idx = (p << 8) + t;
            int k = idx >> 2, ch = idx & 3;
            uint4 vv = *reinterpret_cast<const uint4*>(src + ((size_t)idx << 3));
            *reinterpret_cast<uint4*>(&u.s.B[k][ch << 3]) = vv;
        }
        __syncthreads();
        bf16x8 a = *reinterpret_cast<const bf16x8*>(&u.s.A[(wave << 4) + lr][lg << 3]);
#pragma unroll
        for (int f = 0; f < 16; ++f) {
            bf16x8 bb = *reinterpret_cast<const bf16x8*>(&u.s.B[(f << 4) + lr][lg << 3]);
            acc[f] = __builtin_amdgcn_mfma_f32_16x16x32_bf16(a, bb, acc[f], 0, 0, 0);
        }
    }

    // row inverse norms: threads sharing t>>3 hold same rows (r0, r0+32)
#pragma unroll
    for (int m = 1; m < 8; m <<= 1) { sq0 += __shfl_xor(sq0, m, 64); sq1 += __shfl_xor(sq1, m, 64); }
    if ((lane & 7) == 0) {
        int r0 = t >> 3;
        inv_s[r0] = 1.0f / sqrtf(sq0);
        inv_s[r0 + 32] = 1.0f / sqrtf(sq1);
    }
    __syncthreads();   // also fences last MFMA LDS reads before T-union reuse

    float iv[4];
#pragma unroll
    for (int r = 0; r < 4; ++r) iv[r] = inv_s[(wave << 4) + (lg << 2) + r];

    // softmax over K=256 (logits bounded by |cos|<=~1: skip max-subtract)
    float s[4] = {0.f, 0.f, 0.f, 0.f};
#pragma unroll
    for (int f = 0; f < 16; ++f)
#pragma unroll
        for (int r = 0; r < 4; ++r) {
            float ee = __expf(acc[f][r] * iv[r]);
            acc[f][r] = ee; s[r] += ee;
        }
#pragma unroll
    for (int m = 1; m < 16; m <<= 1)
#pragma unroll
        for (int r = 0; r < 4; ++r) s[r] += __shfl_xor(s[r], m, 64);
    float rs[4];
#pragma unroll
    for (int r = 0; r < 4; ++r) rs[r] = 1.0f / s[r];

    // prob, column sums, transpose into LDS T[col][token]
#pragma unroll
    for (int f = 0; f < 16; ++f) {
        float p0 = acc[f][0] * rs[0], p1 = acc[f][1] * rs[1];
        float p2 = acc[f][2] * rs[2], p3 = acc[f][3] * rs[3];
        float cs = p0 + p1 + p2 + p3;
        cs += __shfl_xor(cs, 16, 64); cs += __shfl_xor(cs, 32, 64);
        if (lg == 0) atomicAdd(&denp[(f << 4) + lr], cs);
        ushort4 w4 = make_ushort4(f2bf(p0), f2bf(p1), f2bf(p2), f2bf(p3));
        *reinterpret_cast<ushort4*>(&u.T[(f << 4) + lr][(wave << 4) + (lg << 2)]) = w4;
    }
    __syncthreads();

    // coalesced writeout of probT tile [256][64]: 256 rows x 8 chunks of 8 u16
    u16* pTb = probT + (size_t)b * 256 * 8192 + n0;
#pragma unroll
    for (int i = 0; i < 8; ++i) {
        int idx = (i << 8) + t;
        int row = idx >> 3, ch = idx & 7;
        uint4 vv = *reinterpret_cast<const uint4*>(&u.T[row][ch << 3]);
        *reinterpret_cast<uint4*>(pTb + (size_t)row * 8192 + (ch << 3)) = vv;
    }
    atomicAdd(&den[(b << 8) + t], denp[t]);
}

// ---------- GEMM2 (LDS-free): num_part[s][b][k][d] = sum_{n in chunk} prob[n][k] * x[n][d] ----------
__global__ __launch_bounds__(256) void k_gemm2(const float* __restrict__ x, const u16* __restrict__ probT,
                                               float* __restrict__ num_part) {
    const int b = blockIdx.z;
    const int s = blockIdx.y;
    const int d0 = blockIdx.x << 6;
    const int t = threadIdx.x;
    const int wave = t >> 6, lane = t & 63;
    const int lg = lane >> 4, lr = lane & 15;

    f32x4 acc[4][4];
#pragma unroll
    for (int m = 0; m < 4; ++m)
#pragma unroll
        for (int tt = 0; tt < 4; ++tt) acc[m][tt] = (f32x4){0.f, 0.f, 0.f, 0.f};

    const int n0 = s << 10;
    const u16* pA = probT + (size_t)b * 256 * 8192;
    const float* xB = x + (size_t)b * 8192 * 768;

    for (int kb = 0; kb < 32; ++kb) {
        int nbase = n0 + (kb << 5);
        bf16x8 a[4];
#pragma unroll
        for (int m = 0; m < 4; ++m) {
            int k = (wave << 6) + (m << 4) + lr;
            a[m] = *reinterpret_cast<const bf16x8*>(pA + (size_t)k * 8192 + nbase + (lg << 3));
        }
        const float* xr = xB + (size_t)(nbase + (lg << 3)) * 768 + d0 + lr;
        bf16x8 bb[4];
#pragma unroll
        for (int tt = 0; tt < 4; ++tt)
#pragma unroll
            for (int j = 0; j < 8; ++j) {
                float f = xr[(size_t)j * 768 + (tt << 4)];
                bb[tt][j] = (short)f2bf(f);
            }
#pragma unroll
        for (int m = 0; m < 4; ++m)
#pragma unroll
            for (int tt = 0; tt < 4; ++tt)
                acc[m][tt] = __builtin_amdgcn_mfma_f32_16x16x32_bf16(a[m], bb[tt], acc[m][tt], 0, 0, 0);
    }

    float* np = num_part + ((size_t)s * 8 + b) * 256 * 768;
#pragma unroll
    for (int m = 0; m < 4; ++m) {
        int kb_ = (wave << 6) + (m << 4) + (lg << 2);
#pragma unroll
        for (int reg = 0; reg < 4; ++reg)
#pragma unroll
            for (int tt = 0; tt < 4; ++tt)
                np[(size_t)(kb_ + reg) * 768 + d0 + (tt << 4) + lr] = acc[m][tt][reg];
    }
}

// ---------- finalize: out = sum_s num_part / (den + eps) ----------
__global__ __launch_bounds__(256) void k_final(const float* __restrict__ num_part, const float* __restrict__ den,
                                               float* __restrict__ out) {
    int i = blockIdx.x * 256 + threadIdx.x;   // < 1,572,864
    float sum = 0.f;
#pragma unroll
    for (int ss = 0; ss < 8; ++ss) sum += num_part[(size_t)ss * 1572864 + i];
    out[i] = sum / (den[i / 768] + 1e-8f);
}

extern "C" void kernel_launch(void* const* d_in, const int* in_sizes, int n_in,
                              void* d_out, int out_size, void* d_ws, size_t ws_size,
                              hipStream_t stream) {
    const float* x = (const float*)d_in[0];
    const float* centers = (const float*)d_in[1];
    float* out = (float*)d_out;
    char* ws = (char*)d_ws;
    u16* cn       = (u16*)ws;                    //  3,145,728 B
    u16* probT    = (u16*)(ws + 3145728);        // 33,554,432 B
    float* den    = (float*)(ws + 36700160);     //      8,192 B
    float* numpt  = (float*)(ws + 36708352);     // 50,331,648 B  (total ~87 MB)

    hipMemsetAsync(den, 0, 8192, stream);
    k_centers<<<512, 256, 0, stream>>>(centers, cn);
    k_gemm1<<<dim3(128, 8), 256, 0, stream>>>(x, cn, probT, den);
    k_gemm2<<<dim3(12, 8, 8), 256, 0, stream>>>(x, probT, numpt);
    k_final<<<6144, 256, 0, stream>>>(numpt, den, out);
}